// Round 1
// baseline (421.611 us; speedup 1.0000x reference)
//
#include <hip/hip_runtime.h>
#include <math.h>

#define NS 10
#define NB 32
#define NG 1000
#define NE 128
#define NH 8
#define MSH 16

// ---------------- Kernel A: Q/K projection ----------------
// Q[n][j] = sum_i ne[n][i] * Wq[j][i];  K likewise. Rows tiled in LDS,
// thread tid<128 -> Q col j=tid, tid>=128 -> K col j=tid-128.
__global__ __launch_bounds__(256) void qk_proj(const float* __restrict__ ne,
                                               const float* __restrict__ Wq,
                                               const float* __restrict__ Wk,
                                               float* __restrict__ Q,
                                               float* __restrict__ K) {
    __shared__ float4 A4[32][32];   // 32 rows x 128 floats
    const int tid = threadIdx.x;
    const int r0 = blockIdx.x * 32;
    const float4* src = (const float4*)(ne + (size_t)r0 * NE);
    float4* a = &A4[0][0];
    for (int i = tid; i < 32 * 32; i += 256) a[i] = src[i];
    __syncthreads();

    const int j = tid & 127;
    const float4* W4 = (const float4*)((tid < 128) ? Wq : Wk) + j * 32;
    float* Out = ((tid < 128) ? Q : K) + j;

    float acc[32];
#pragma unroll
    for (int r = 0; r < 32; ++r) acc[r] = 0.f;

    for (int i4 = 0; i4 < 32; ++i4) {
        float4 w = W4[i4];
#pragma unroll
        for (int r = 0; r < 32; ++r) {
            float4 av = A4[r][i4];
            acc[r] += av.x * w.x + av.y * w.y + av.z * w.z + av.w * w.w;
        }
    }
#pragma unroll
    for (int r = 0; r < 32; ++r) Out[(size_t)(r0 + r) * NE] = acc[r];
}

// ---------------- Kernel B: per-edge scoring ----------------
// For each (s,b,t): src=sol[t], dst=sol[t+1 mod G]; dot per head from gathered
// Q/K rows; 2->16->1 MLP per head; e = sum_h ms2*nw; val = e/costs[s][b].
// Write val/dst indexed by src (bijective per (s,b): no races).
__global__ __launch_bounds__(256) void edge_score(
        const int* __restrict__ sol, const float* __restrict__ costs,
        const float* __restrict__ dist,
        const float* __restrict__ Q, const float* __restrict__ K,
        const float* __restrict__ m1w, const float* __restrict__ m1b,
        const float* __restrict__ m2w, const float* __restrict__ m2b,
        const float* __restrict__ nhw,
        float* __restrict__ val_buf, int* __restrict__ dst_buf) {
    __shared__ float w1[NH][2][MSH];   // 256
    __shared__ float b1[NH][MSH];      // 128
    __shared__ float w2[NH][MSH];      // 128
    __shared__ float b2[NH];
    __shared__ float nw[NH];
    const int tid = threadIdx.x;
    if (tid < 256) ((float*)w1)[tid] = m1w[tid];
    if (tid < 128) { ((float*)b1)[tid] = m1b[tid]; ((float*)w2)[tid] = m2w[tid]; }
    if (tid < NH)  { b2[tid] = m2b[tid]; nw[tid] = nhw[tid]; }
    __syncthreads();

    const int gidx = blockIdx.x * 256 + tid;
    if (gidx >= NS * NB * NG) return;
    const int s   = gidx / (NB * NG);
    const int rem = gidx - s * (NB * NG);
    const int b   = rem / NG;
    const int t   = rem - b * NG;

    const int* srow = sol + (size_t)(s * NB + b) * NG;
    const int src = srow[t];
    int tn = t + 1; if (tn == NG) tn = 0;
    const int dst = srow[tn];

    const float4* Qr = (const float4*)(Q + (size_t)(b * NG + src) * NE);
    const float4* Kr = (const float4*)(K + (size_t)(b * NG + dst) * NE);
    const float edge = dist[(size_t)(b * NG + src) * NG + dst];

    float e = 0.f;
#pragma unroll
    for (int h = 0; h < NH; ++h) {
        float d = 0.f;
#pragma unroll
        for (int i4 = 0; i4 < 4; ++i4) {
            float4 q = Qr[h * 4 + i4];
            float4 k = Kr[h * 4 + i4];
            d += q.x * k.x + q.y * k.y + q.z * k.z + q.w * k.w;
        }
        d *= 0.0625f;   // norm_factor/sqrt_qkv = (1/4)/4
        float ms2 = b2[h];
#pragma unroll
        for (int m = 0; m < MSH; ++m) {
            float v = d * w1[h][0][m] + edge * w1[h][1][m] + b1[h][m];
            v = fmaxf(v, 0.f);
            ms2 += v * w2[h][m];
        }
        e += ms2 * nw[h];
    }
    const float val = e / costs[s * NB + b];
    const size_t o = (size_t)(s * NB + b) * NG + src;
    val_buf[o] = val;
    dst_buf[o] = dst;
}

// ---------------- Kernel C: sparse softmax + aggregate ----------------
// One wave per (b, src) row. 10 candidate (dst, val); merge equal dsts (scatter
// -add), exclude exact-zero sums (attn != 0 -> NEG), softmax over survivors,
// weighted sum of node_embed rows. Lane handles dims (lane, lane+64).
__global__ __launch_bounds__(256) void sparse_softmax_agg(
        const float* __restrict__ val_buf, const int* __restrict__ dst_buf,
        const float* __restrict__ ne, float* __restrict__ solu) {
    const int w = (blockIdx.x * 256 + threadIdx.x) >> 6;
    const int lane = threadIdx.x & 63;
    if (w >= NB * NG) return;
    const int b = w / NG;
    const int g = w - b * NG;

    float v[NS];
    int d[NS];
#pragma unroll
    for (int s = 0; s < NS; ++s) {
        const size_t o = (size_t)(s * NB + b) * NG + g;
        v[s] = val_buf[o];
        d[s] = dst_buf[o];
    }
    unsigned keep = (1u << NS) - 1u;
#pragma unroll
    for (int s = 1; s < NS; ++s) {
#pragma unroll
        for (int p = 0; p < s; ++p) {
            if (((keep >> s) & 1u) && ((keep >> p) & 1u) && (d[s] == d[p])) {
                v[p] += v[s];
                keep &= ~(1u << s);
            }
        }
    }
    float m = -INFINITY;
#pragma unroll
    for (int s = 0; s < NS; ++s) {
        const bool ok = ((keep >> s) & 1u) && (v[s] != 0.f);
        if (!ok) keep &= ~(1u << s);
        else m = fmaxf(m, v[s]);
    }

    float a0 = 0.f, a1 = 0.f;
    if (keep == 0u) {
        // entire row was NEG -> uniform softmax over all G nodes (never in
        // practice; correctness fallback)
        const float* base = ne + (size_t)b * NG * NE;
        for (int n = 0; n < NG; ++n) {
            a0 += base[(size_t)n * NE + lane];
            a1 += base[(size_t)n * NE + 64 + lane];
        }
        const float invG = 1.f / NG;
        a0 *= invG; a1 *= invG;
    } else {
        float p[NS];
        float denom = 0.f;
#pragma unroll
        for (int s = 0; s < NS; ++s) {
            p[s] = ((keep >> s) & 1u) ? expf(v[s] - m) : 0.f;
            denom += p[s];
        }
        const float inv = 1.f / denom;
#pragma unroll
        for (int s = 0; s < NS; ++s) {
            if ((keep >> s) & 1u) {
                const float* r = ne + (size_t)(b * NG + d[s]) * NE;
                const float wt = p[s] * inv;
                a0 += wt * r[lane];
                a1 += wt * r[64 + lane];
            }
        }
    }
    solu[(size_t)w * NE + lane] = a0;
    solu[(size_t)w * NE + 64 + lane] = a1;
}

// ---------------- Kernel D: GRU cell + ELU ----------------
// 128 threads: thread j owns output dim j. 16 rows/block staged in LDS.
// 6 accumulators per row: (i_r,i_z,i_n) from x@W_ih^T, (h_r,h_z,h_n) from
// h@W_hh^T.
#define ROWS_D 16
__global__ __launch_bounds__(128) void gru_cell(
        const float* __restrict__ x_in, const float* __restrict__ h_in,
        const float* __restrict__ wih, const float* __restrict__ whh,
        const float* __restrict__ bih, const float* __restrict__ bhh,
        float* __restrict__ out0, float* __restrict__ out1) {
    __shared__ float4 xl[ROWS_D][32];
    __shared__ float4 hl[ROWS_D][32];
    const int tid = threadIdx.x;
    const int r0 = blockIdx.x * ROWS_D;
    const float4* xs = (const float4*)(x_in + (size_t)r0 * NE);
    const float4* hs = (const float4*)(h_in + (size_t)r0 * NE);
    for (int i = tid; i < ROWS_D * 32; i += 128) {
        (&xl[0][0])[i] = xs[i];
        (&hl[0][0])[i] = hs[i];
    }
    __syncthreads();

    const int j = tid;
    const float4* wi0 = (const float4*)wih + (size_t)j * 32;
    const float4* wi1 = (const float4*)wih + (size_t)(128 + j) * 32;
    const float4* wi2 = (const float4*)wih + (size_t)(256 + j) * 32;
    const float4* wh0 = (const float4*)whh + (size_t)j * 32;
    const float4* wh1 = (const float4*)whh + (size_t)(128 + j) * 32;
    const float4* wh2 = (const float4*)whh + (size_t)(256 + j) * 32;

    float ar[ROWS_D][6];
#pragma unroll
    for (int r = 0; r < ROWS_D; ++r)
#pragma unroll
        for (int q = 0; q < 6; ++q) ar[r][q] = 0.f;

    for (int i4 = 0; i4 < 32; ++i4) {
        const float4 wa = wi0[i4], wb = wi1[i4], wc = wi2[i4];
        const float4 wd = wh0[i4], we = wh1[i4], wf = wh2[i4];
#pragma unroll
        for (int r = 0; r < ROWS_D; ++r) {
            const float4 x4 = xl[r][i4];
            const float4 h4 = hl[r][i4];
            ar[r][0] += x4.x * wa.x + x4.y * wa.y + x4.z * wa.z + x4.w * wa.w;
            ar[r][1] += x4.x * wb.x + x4.y * wb.y + x4.z * wb.z + x4.w * wb.w;
            ar[r][2] += x4.x * wc.x + x4.y * wc.y + x4.z * wc.z + x4.w * wc.w;
            ar[r][3] += h4.x * wd.x + h4.y * wd.y + h4.z * wd.z + h4.w * wd.w;
            ar[r][4] += h4.x * we.x + h4.y * we.y + h4.z * we.z + h4.w * we.w;
            ar[r][5] += h4.x * wf.x + h4.y * wf.y + h4.z * wf.z + h4.w * wf.w;
        }
    }

    const float bi0 = bih[j], bi1 = bih[128 + j], bi2 = bih[256 + j];
    const float bh0 = bhh[j], bh1 = bhh[128 + j], bh2 = bhh[256 + j];
#pragma unroll
    for (int r = 0; r < ROWS_D; ++r) {
        const float ir = ar[r][0] + bi0;
        const float iz = ar[r][1] + bi1;
        const float in_ = ar[r][2] + bi2;
        const float hr = ar[r][3] + bh0;
        const float hz = ar[r][4] + bh1;
        const float hn = ar[r][5] + bh2;
        const float rr = 1.f / (1.f + expf(-(ir + hr)));
        const float zz = 1.f / (1.f + expf(-(iz + hz)));
        const float nn = tanhf(in_ + rr * hn);
        const float hv = ((const float*)&hl[r][0])[j];
        const float nv = (1.f - zz) * nn + zz * hv;
        const size_t o = (size_t)(r0 + r) * NE + j;
        out1[o] = nv;
        out0[o] = (nv > 0.f) ? nv : expm1f(nv);
    }
}

extern "C" void kernel_launch(void* const* d_in, const int* in_sizes, int n_in,
                              void* d_out, int out_size, void* d_ws, size_t ws_size,
                              hipStream_t stream) {
    const float* ne    = (const float*)d_in[0];
    const int*   sol   = (const int*)d_in[1];
    const float* costs = (const float*)d_in[2];
    const float* dist  = (const float*)d_in[3];
    const float* old_h = (const float*)d_in[4];
    const float* Wq    = (const float*)d_in[5];
    const float* Wk    = (const float*)d_in[6];
    const float* m1w   = (const float*)d_in[7];
    const float* m1b   = (const float*)d_in[8];
    const float* m2w   = (const float*)d_in[9];
    const float* m2b   = (const float*)d_in[10];
    const float* nhw   = (const float*)d_in[11];
    const float* wih   = (const float*)d_in[12];
    const float* whh   = (const float*)d_in[13];
    const float* bih   = (const float*)d_in[14];
    const float* bhh   = (const float*)d_in[15];

    float* out0 = (float*)d_out;                       // elu(new)
    float* out1 = out0 + (size_t)NB * NG * NE;         // new

    // workspace layout (all 16B-aligned)
    float* Q       = (float*)d_ws;                               // 16.384 MB
    float* K       = Q + (size_t)NB * NG * NE;                   // 16.384 MB
    float* val_buf = K + (size_t)NB * NG * NE;                   // 1.28 MB
    int*   dst_buf = (int*)(val_buf + (size_t)NS * NB * NG);     // 1.28 MB
    float* solu    = (float*)(dst_buf + (size_t)NS * NB * NG);   // 16.384 MB

    qk_proj<<<(NB * NG) / 32, 256, 0, stream>>>(ne, Wq, Wk, Q, K);
    edge_score<<<(NS * NB * NG + 255) / 256, 256, 0, stream>>>(
        sol, costs, dist, Q, K, m1w, m1b, m2w, m2b, nhw, val_buf, dst_buf);
    sparse_softmax_agg<<<(NB * NG * 64) / 256, 256, 0, stream>>>(
        val_buf, dst_buf, ne, solu);
    gru_cell<<<(NB * NG) / ROWS_D, 128, 0, stream>>>(
        solu, old_h, wih, whh, bih, bhh, out0, out1);
}

// Round 3
// 177.205 us; speedup vs baseline: 2.3792x; 2.3792x over previous
//
#include <hip/hip_runtime.h>
#include <math.h>

#define NS 10
#define NB 32
#define NG 1000
#define NE 128
#define NH 8
#define MSH 16

typedef __bf16 bf16x8 __attribute__((ext_vector_type(8)));
typedef float f32x4 __attribute__((ext_vector_type(4)));
typedef unsigned short ushort;
typedef ushort us8 __attribute__((ext_vector_type(8)));

__device__ __forceinline__ ushort f2bf(float f) {
    union { float f; unsigned u; } c; c.f = f;
    unsigned r = c.u + 0x7FFFu + ((c.u >> 16) & 1u);
    return (ushort)(r >> 16);
}

// ---------------- Kernel W: weight conversion f32 -> bf16 ----------------
// Wq,Wk -> Wqk_b [256][128]; wih -> wih_b [384][128]; whh -> whh_b.
__global__ __launch_bounds__(256) void wcvt(const float* __restrict__ Wq,
                                            const float* __restrict__ Wk,
                                            const float* __restrict__ wih,
                                            const float* __restrict__ whh,
                                            ushort* __restrict__ Wqk_b,
                                            ushort* __restrict__ wih_b,
                                            ushort* __restrict__ whh_b) {
    const int tid = blockIdx.x * 256 + threadIdx.x;   // 64 blocks * 256 = 16384
    const int e = tid * 8;
    const float* src; ushort* dst; int off;
    if (e < 16384)       { src = Wq;  dst = Wqk_b;        off = e; }
    else if (e < 32768)  { src = Wk;  dst = Wqk_b + 16384; off = e - 16384; }
    else if (e < 81920)  { src = wih; dst = wih_b;        off = e - 32768; }
    else                 { src = whh; dst = whh_b;        off = e - 81920; }
    const float4 f0 = ((const float4*)(src + off))[0];
    const float4 f1 = ((const float4*)(src + off))[1];
    us8 v;
    v[0] = f2bf(f0.x); v[1] = f2bf(f0.y); v[2] = f2bf(f0.z); v[3] = f2bf(f0.w);
    v[4] = f2bf(f1.x); v[5] = f2bf(f1.y); v[6] = f2bf(f1.z); v[7] = f2bf(f1.w);
    *(us8*)(dst + off) = v;
}

// ---------------- Kernel A: Q/K projection via MFMA ----------------
// QK[row][0:128]=Q, [128:256]=K.  32-row tile, 8 waves, wave w -> cols [32w,32w+32).
__global__ __launch_bounds__(512) void qk_mfma(const float* __restrict__ ne,
                                               const ushort* __restrict__ Wqk_b,
                                               float* __restrict__ QK) {
    __shared__ __align__(16) ushort A[32 * 128];
    const int tid = threadIdx.x;
    const int rowbase = blockIdx.x * 32;

    // stage: f32 -> bf16, XOR-swizzled chunks (16B chunk c at row r -> c^(r&7))
    {
        const int r = tid >> 4, kc = tid & 15;
        const float4* s4 = (const float4*)(ne + (size_t)(rowbase + r) * NE);
        const float4 f0 = s4[kc * 2], f1 = s4[kc * 2 + 1];
        us8 v;
        v[0] = f2bf(f0.x); v[1] = f2bf(f0.y); v[2] = f2bf(f0.z); v[3] = f2bf(f0.w);
        v[4] = f2bf(f1.x); v[5] = f2bf(f1.y); v[6] = f2bf(f1.z); v[7] = f2bf(f1.w);
        *(us8*)&A[(r * 16 + (kc ^ (r & 7))) * 8] = v;
    }
    __syncthreads();

    const int w = tid >> 6, l = tid & 63;
    const int lr = l & 15, lg = l >> 4;

    f32x4 acc[2][2] = {};
#pragma unroll
    for (int ks = 0; ks < 4; ++ks) {
        bf16x8 a[2], b[2];
#pragma unroll
        for (int mf = 0; mf < 2; ++mf) {
            const int r = mf * 16 + lr;
            a[mf] = *(const bf16x8*)&A[(r * 16 + ((ks * 4 + lg) ^ (r & 7))) * 8];
        }
#pragma unroll
        for (int nf = 0; nf < 2; ++nf) {
            const int j = w * 32 + nf * 16 + lr;
            b[nf] = *(const bf16x8*)&Wqk_b[(size_t)j * 128 + ks * 32 + lg * 8];
        }
#pragma unroll
        for (int mf = 0; mf < 2; ++mf)
#pragma unroll
            for (int nf = 0; nf < 2; ++nf)
                acc[mf][nf] = __builtin_amdgcn_mfma_f32_16x16x32_bf16(a[mf], b[nf], acc[mf][nf], 0, 0, 0);
    }
#pragma unroll
    for (int mf = 0; mf < 2; ++mf)
#pragma unroll
        for (int nf = 0; nf < 2; ++nf)
#pragma unroll
            for (int q = 0; q < 4; ++q) {
                const int row = rowbase + mf * 16 + lg * 4 + q;
                const int col = w * 32 + nf * 16 + lr;
                QK[(size_t)row * 256 + col] = acc[mf][nf][q];
            }
}

// ---------------- Kernel B: per-edge scoring ----------------
__global__ __launch_bounds__(256) void edge_score(
        const int* __restrict__ sol, const float* __restrict__ costs,
        const float* __restrict__ dist, const float* __restrict__ QK,
        const float* __restrict__ m1w, const float* __restrict__ m1b,
        const float* __restrict__ m2w, const float* __restrict__ m2b,
        const float* __restrict__ nhw,
        float* __restrict__ val_buf, int* __restrict__ dst_buf) {
    __shared__ float w1[NH][2][MSH];
    __shared__ float b1[NH][MSH];
    __shared__ float w2[NH][MSH];
    __shared__ float b2[NH];
    __shared__ float nw[NH];
    const int tid = threadIdx.x;
    ((float*)w1)[tid] = m1w[tid];
    if (tid < 128) { ((float*)b1)[tid] = m1b[tid]; ((float*)w2)[tid] = m2w[tid]; }
    if (tid < NH)  { b2[tid] = m2b[tid]; nw[tid] = nhw[tid]; }
    __syncthreads();

    const int gidx = blockIdx.x * 256 + tid;
    if (gidx >= NS * NB * NG) return;
    const int s   = gidx / (NB * NG);
    const int rem = gidx - s * (NB * NG);
    const int b   = rem / NG;
    const int t   = rem - b * NG;

    const int* srow = sol + (size_t)(s * NB + b) * NG;
    const int src = srow[t];
    int tn = t + 1; if (tn == NG) tn = 0;
    const int dst = srow[tn];

    const float4* Qr = (const float4*)(QK + (size_t)(b * NG + src) * 256);
    const float4* Kr = (const float4*)(QK + (size_t)(b * NG + dst) * 256 + 128);
    const float edge = dist[(size_t)(b * NG + src) * NG + dst];

    float e = 0.f;
#pragma unroll
    for (int h = 0; h < NH; ++h) {
        float d = 0.f;
#pragma unroll
        for (int i4 = 0; i4 < 4; ++i4) {
            float4 q = Qr[h * 4 + i4];
            float4 k = Kr[h * 4 + i4];
            d += q.x * k.x + q.y * k.y + q.z * k.z + q.w * k.w;
        }
        d *= 0.0625f;
        float ms2 = b2[h];
#pragma unroll
        for (int m = 0; m < MSH; ++m) {
            float v = d * w1[h][0][m] + edge * w1[h][1][m] + b1[h][m];
            v = fmaxf(v, 0.f);
            ms2 += v * w2[h][m];
        }
        e += ms2 * nw[h];
    }
    const float val = e / costs[s * NB + b];
    const size_t o = (size_t)(s * NB + b) * NG + src;
    val_buf[o] = val;
    dst_buf[o] = dst;
}

// ---------------- Kernel C: sparse softmax + aggregate (-> bf16) ----------------
// One wave per (b,src) row; lane owns dims (2l, 2l+1); writes packed bf16x2.
__global__ __launch_bounds__(256) void sparse_softmax_agg(
        const float* __restrict__ val_buf, const int* __restrict__ dst_buf,
        const float* __restrict__ ne, unsigned* __restrict__ solu_b) {
    const int w = (blockIdx.x * 256 + threadIdx.x) >> 6;
    const int lane = threadIdx.x & 63;
    if (w >= NB * NG) return;
    const int b = w / NG;
    const int g = w - b * NG;

    float v[NS];
    int d[NS];
#pragma unroll
    for (int s = 0; s < NS; ++s) {
        const size_t o = (size_t)(s * NB + b) * NG + g;
        v[s] = val_buf[o];
        d[s] = dst_buf[o];
    }
    unsigned keep = (1u << NS) - 1u;
#pragma unroll
    for (int s = 1; s < NS; ++s) {
#pragma unroll
        for (int p = 0; p < s; ++p) {
            if (((keep >> s) & 1u) && ((keep >> p) & 1u) && (d[s] == d[p])) {
                v[p] += v[s];
                keep &= ~(1u << s);
            }
        }
    }
    float m = -INFINITY;
#pragma unroll
    for (int s = 0; s < NS; ++s) {
        const bool ok = ((keep >> s) & 1u) && (v[s] != 0.f);
        if (!ok) keep &= ~(1u << s);
        else m = fmaxf(m, v[s]);
    }

    float a0 = 0.f, a1 = 0.f;
    if (keep == 0u) {
        const float2* base = (const float2*)(ne + (size_t)b * NG * NE);
        for (int n = 0; n < NG; ++n) {
            float2 r = base[n * 64 + lane];
            a0 += r.x; a1 += r.y;
        }
        const float invG = 1.f / NG;
        a0 *= invG; a1 *= invG;
    } else {
        float p[NS];
        float denom = 0.f;
#pragma unroll
        for (int s = 0; s < NS; ++s) {
            p[s] = ((keep >> s) & 1u) ? expf(v[s] - m) : 0.f;
            denom += p[s];
        }
        const float inv = 1.f / denom;
#pragma unroll
        for (int s = 0; s < NS; ++s) {
            if ((keep >> s) & 1u) {
                const float2 r = ((const float2*)(ne + (size_t)(b * NG + d[s]) * NE))[lane];
                const float wt = p[s] * inv;
                a0 += wt * r.x;
                a1 += wt * r.y;
            }
        }
    }
    solu_b[(size_t)w * 64 + lane] = (unsigned)f2bf(a0) | ((unsigned)f2bf(a1) << 16);
}

// ---------------- Kernel D: fused GRU via MFMA ----------------
// 32-row tile, 8 waves. Wave w owns cols j in [16w,16w+16) and computes all 6
// gate pre-activations (12 fragments) then applies gates in-register.
__global__ __launch_bounds__(512) void gru_mfma(
        const ushort* __restrict__ x_b,      // solu bf16 [32000][128]
        const float* __restrict__ h_in,      // f32 [32000][128]
        const ushort* __restrict__ wih_b, const ushort* __restrict__ whh_b,
        const float* __restrict__ bih, const float* __restrict__ bhh,
        float* __restrict__ out0, float* __restrict__ out1) {
    __shared__ __align__(16) ushort X[32 * 128];
    __shared__ __align__(16) ushort H[32 * 128];
    const int tid = threadIdx.x;
    const int rowbase = blockIdx.x * 32;

    {
        const int r = tid >> 4, kc = tid & 15;
        // x: already bf16
        us8 xv = *(const us8*)&x_b[(size_t)(rowbase + r) * NE + kc * 8];
        *(us8*)&X[(r * 16 + (kc ^ (r & 7))) * 8] = xv;
        // h: f32 -> bf16
        const float4* h4 = (const float4*)(h_in + (size_t)(rowbase + r) * NE);
        const float4 f0 = h4[kc * 2], f1 = h4[kc * 2 + 1];
        us8 hv;
        hv[0] = f2bf(f0.x); hv[1] = f2bf(f0.y); hv[2] = f2bf(f0.z); hv[3] = f2bf(f0.w);
        hv[4] = f2bf(f1.x); hv[5] = f2bf(f1.y); hv[6] = f2bf(f1.z); hv[7] = f2bf(f1.w);
        *(us8*)&H[(r * 16 + (kc ^ (r & 7))) * 8] = hv;
    }
    __syncthreads();

    const int w = tid >> 6, l = tid & 63;
    const int lr = l & 15, lg = l >> 4;
    const int j = w * 16 + lr;          // this lane's output column

    f32x4 acc[2][6] = {};
#pragma unroll
    for (int ks = 0; ks < 4; ++ks) {
        bf16x8 ax[2], ah[2], bb[6];
#pragma unroll
        for (int mf = 0; mf < 2; ++mf) {
            const int r = mf * 16 + lr;
            const int c = (r * 16 + ((ks * 4 + lg) ^ (r & 7))) * 8;
            ax[mf] = *(const bf16x8*)&X[c];
            ah[mf] = *(const bf16x8*)&H[c];
        }
#pragma unroll
        for (int g = 0; g < 3; ++g) {
            bb[g]     = *(const bf16x8*)&wih_b[(size_t)(g * 128 + j) * 128 + ks * 32 + lg * 8];
            bb[g + 3] = *(const bf16x8*)&whh_b[(size_t)(g * 128 + j) * 128 + ks * 32 + lg * 8];
        }
#pragma unroll
        for (int mf = 0; mf < 2; ++mf) {
#pragma unroll
            for (int g = 0; g < 3; ++g) {
                acc[mf][g]     = __builtin_amdgcn_mfma_f32_16x16x32_bf16(ax[mf], bb[g],     acc[mf][g],     0, 0, 0);
                acc[mf][g + 3] = __builtin_amdgcn_mfma_f32_16x16x32_bf16(ah[mf], bb[g + 3], acc[mf][g + 3], 0, 0, 0);
            }
        }
    }

    const float bi0 = bih[j], bi1 = bih[128 + j], bi2 = bih[256 + j];
    const float bh0 = bhh[j], bh1 = bhh[128 + j], bh2 = bhh[256 + j];
#pragma unroll
    for (int mf = 0; mf < 2; ++mf) {
#pragma unroll
        for (int q = 0; q < 4; ++q) {
            const int row = rowbase + mf * 16 + lg * 4 + q;
            const float ir = acc[mf][0][q] + bi0;
            const float iz = acc[mf][1][q] + bi1;
            const float in_ = acc[mf][2][q] + bi2;
            const float hr = acc[mf][3][q] + bh0;
            const float hz = acc[mf][4][q] + bh1;
            const float hn = acc[mf][5][q] + bh2;
            const float rr = 1.f / (1.f + expf(-(ir + hr)));
            const float zz = 1.f / (1.f + expf(-(iz + hz)));
            const float nn = tanhf(in_ + rr * hn);
            const float hv = h_in[(size_t)row * NE + j];
            const float nv = (1.f - zz) * nn + zz * hv;
            const size_t o = (size_t)row * NE + j;
            out1[o] = nv;
            out0[o] = (nv > 0.f) ? nv : expm1f(nv);
        }
    }
}

extern "C" void kernel_launch(void* const* d_in, const int* in_sizes, int n_in,
                              void* d_out, int out_size, void* d_ws, size_t ws_size,
                              hipStream_t stream) {
    const float* ne    = (const float*)d_in[0];
    const int*   sol   = (const int*)d_in[1];
    const float* costs = (const float*)d_in[2];
    const float* dist  = (const float*)d_in[3];
    const float* old_h = (const float*)d_in[4];
    const float* Wq    = (const float*)d_in[5];
    const float* Wk    = (const float*)d_in[6];
    const float* m1w   = (const float*)d_in[7];
    const float* m1b   = (const float*)d_in[8];
    const float* m2w   = (const float*)d_in[9];
    const float* m2b   = (const float*)d_in[10];
    const float* nhw   = (const float*)d_in[11];
    const float* wih   = (const float*)d_in[12];
    const float* whh   = (const float*)d_in[13];
    const float* bih   = (const float*)d_in[14];
    const float* bhh   = (const float*)d_in[15];

    float* out0 = (float*)d_out;
    float* out1 = out0 + (size_t)NB * NG * NE;

    // workspace layout (16B aligned)
    float*   QK      = (float*)d_ws;                                   // 32.768 MB
    float*   val_buf = QK + (size_t)NB * NG * 256;                     // 1.28 MB
    int*     dst_buf = (int*)(val_buf + (size_t)NS * NB * NG);         // 1.28 MB
    unsigned* solu_b = (unsigned*)(dst_buf + (size_t)NS * NB * NG);    // 8.192 MB
    ushort*  Wqk_b   = (ushort*)(solu_b + (size_t)NB * NG * 64);       // 64 KB
    ushort*  wih_b   = Wqk_b + 256 * 128;                              // 96 KB
    ushort*  whh_b   = wih_b + 384 * 128;                              // 96 KB

    wcvt<<<64, 256, 0, stream>>>(Wq, Wk, wih, whh, Wqk_b, wih_b, whh_b);
    qk_mfma<<<(NB * NG) / 32, 512, 0, stream>>>(ne, Wqk_b, QK);
    edge_score<<<(NS * NB * NG + 255) / 256, 256, 0, stream>>>(
        sol, costs, dist, QK, m1w, m1b, m2w, m2b, nhw, val_buf, dst_buf);
    sparse_softmax_agg<<<(NB * NG * 64) / 256, 256, 0, stream>>>(
        val_buf, dst_buf, ne, solu_b);
    gru_mfma<<<(NB * NG) / 32, 512, 0, stream>>>(
        (const ushort*)solu_b, old_h, wih_b, whh_b, bih, bhh, out0, out1);
}

// Round 4
// 160.002 us; speedup vs baseline: 2.6350x; 1.1075x over previous
//
#include <hip/hip_runtime.h>
#include <math.h>

#define NS 10
#define NB 32
#define NG 1000
#define NE 128
#define NH 8
#define MSH 16

typedef __bf16 bf16x8 __attribute__((ext_vector_type(8)));
typedef float f32x4 __attribute__((ext_vector_type(4)));
typedef unsigned short ushort;
typedef ushort us8 __attribute__((ext_vector_type(8)));

__device__ __forceinline__ ushort f2bf(float f) {
    union { float f; unsigned u; } c; c.f = f;
    unsigned r = c.u + 0x7FFFu + ((c.u >> 16) & 1u);
    return (ushort)(r >> 16);
}
__device__ __forceinline__ float bflo(unsigned u) {
    union { unsigned v; float f; } c; c.v = u << 16; return c.f;
}
__device__ __forceinline__ float bfhi(unsigned u) {
    union { unsigned v; float f; } c; c.v = u & 0xFFFF0000u; return c.f;
}

// ---------------- Kernel W: weight conversion f32 -> bf16 ----------------
__global__ __launch_bounds__(256) void wcvt(const float* __restrict__ Wq,
                                            const float* __restrict__ Wk,
                                            const float* __restrict__ wih,
                                            const float* __restrict__ whh,
                                            ushort* __restrict__ Wqk_b,
                                            ushort* __restrict__ wih_b,
                                            ushort* __restrict__ whh_b) {
    const int tid = blockIdx.x * 256 + threadIdx.x;   // 64 blocks * 256 = 16384
    const int e = tid * 8;
    const float* src; ushort* dst; int off;
    if (e < 16384)       { src = Wq;  dst = Wqk_b;        off = e; }
    else if (e < 32768)  { src = Wk;  dst = Wqk_b + 16384; off = e - 16384; }
    else if (e < 81920)  { src = wih; dst = wih_b;        off = e - 32768; }
    else                 { src = whh; dst = whh_b;        off = e - 81920; }
    const float4 f0 = ((const float4*)(src + off))[0];
    const float4 f1 = ((const float4*)(src + off))[1];
    us8 v;
    v[0] = f2bf(f0.x); v[1] = f2bf(f0.y); v[2] = f2bf(f0.z); v[3] = f2bf(f0.w);
    v[4] = f2bf(f1.x); v[5] = f2bf(f1.y); v[6] = f2bf(f1.z); v[7] = f2bf(f1.w);
    *(us8*)(dst + off) = v;
}

// ---------------- succ_build: succ[s][b][src] = dst ----------------
__global__ __launch_bounds__(256) void succ_build(const int* __restrict__ sol,
                                                  int* __restrict__ succ) {
    const int gidx = blockIdx.x * 256 + threadIdx.x;   // (s*NB+b)*NG + t
    if (gidx >= NS * NB * NG) return;
    const int sb = gidx / NG;
    const int t = gidx - sb * NG;
    const int* srow = sol + (size_t)sb * NG;
    const int src = srow[t];
    const int tn = (t + 1 == NG) ? 0 : t + 1;
    succ[(size_t)sb * NG + src] = srow[tn];
}

// ---------------- Kernel A: Q/K projection via MFMA -> bf16 ----------------
// QKb[row][0:128]=Q, [128:256]=K (bf16). Also emits ne_b (bf16 copy of ne).
__global__ __launch_bounds__(512) void qk_mfma(const float* __restrict__ ne,
                                               const ushort* __restrict__ Wqk_b,
                                               ushort* __restrict__ QKb,
                                               ushort* __restrict__ ne_b) {
    __shared__ __align__(16) ushort A[32 * 128];
    const int tid = threadIdx.x;
    const int rowbase = blockIdx.x * 32;

    {
        const int r = tid >> 4, kc = tid & 15;
        const float4* s4 = (const float4*)(ne + (size_t)(rowbase + r) * NE);
        const float4 f0 = s4[kc * 2], f1 = s4[kc * 2 + 1];
        us8 v;
        v[0] = f2bf(f0.x); v[1] = f2bf(f0.y); v[2] = f2bf(f0.z); v[3] = f2bf(f0.w);
        v[4] = f2bf(f1.x); v[5] = f2bf(f1.y); v[6] = f2bf(f1.z); v[7] = f2bf(f1.w);
        *(us8*)&A[(r * 16 + (kc ^ (r & 7))) * 8] = v;
        *(us8*)&ne_b[(size_t)(rowbase + r) * NE + kc * 8] = v;   // bf16 node_embed
    }
    __syncthreads();

    const int w = tid >> 6, l = tid & 63;
    const int lr = l & 15, lg = l >> 4;

    f32x4 acc[2][2] = {};
#pragma unroll
    for (int ks = 0; ks < 4; ++ks) {
        bf16x8 a[2], b[2];
#pragma unroll
        for (int mf = 0; mf < 2; ++mf) {
            const int r = mf * 16 + lr;
            a[mf] = *(const bf16x8*)&A[(r * 16 + ((ks * 4 + lg) ^ (r & 7))) * 8];
        }
#pragma unroll
        for (int nf = 0; nf < 2; ++nf) {
            const int j = w * 32 + nf * 16 + lr;
            b[nf] = *(const bf16x8*)&Wqk_b[(size_t)j * 128 + ks * 32 + lg * 8];
        }
#pragma unroll
        for (int mf = 0; mf < 2; ++mf)
#pragma unroll
            for (int nf = 0; nf < 2; ++nf)
                acc[mf][nf] = __builtin_amdgcn_mfma_f32_16x16x32_bf16(a[mf], b[nf], acc[mf][nf], 0, 0, 0);
    }
#pragma unroll
    for (int mf = 0; mf < 2; ++mf)
#pragma unroll
        for (int nf = 0; nf < 2; ++nf)
#pragma unroll
            for (int q = 0; q < 4; ++q) {
                const int row = rowbase + mf * 16 + lg * 4 + q;
                const int col = w * 32 + nf * 16 + lr;
                QKb[(size_t)row * 256 + col] = f2bf(acc[mf][nf][q]);
            }
}

// ---------------- Kernel B: per-edge scoring, src-major ----------------
// gidx = (s*NB+b)*NG + src  -> Q-row reads sequential, K gathered via succ.
__global__ __launch_bounds__(256) void edge_score2(
        const int* __restrict__ succ, const float* __restrict__ costs,
        const float* __restrict__ dist, const ushort* __restrict__ QKb,
        const float* __restrict__ m1w, const float* __restrict__ m1b,
        const float* __restrict__ m2w, const float* __restrict__ m2b,
        const float* __restrict__ nhw,
        float* __restrict__ val_buf, int* __restrict__ dst_buf) {
    __shared__ float w1[NH][2][MSH];
    __shared__ float b1[NH][MSH];
    __shared__ float w2[NH][MSH];
    __shared__ float b2[NH];
    __shared__ float nw[NH];
    const int tid = threadIdx.x;
    ((float*)w1)[tid] = m1w[tid];
    if (tid < 128) { ((float*)b1)[tid] = m1b[tid]; ((float*)w2)[tid] = m2w[tid]; }
    if (tid < NH)  { b2[tid] = m2b[tid]; nw[tid] = nhw[tid]; }
    __syncthreads();

    const int gidx = blockIdx.x * 256 + tid;
    if (gidx >= NS * NB * NG) return;
    const int sb = gidx / NG;          // s*NB + b
    const int src = gidx - sb * NG;
    const int s = sb >> 5;             // NB = 32
    const int b = sb & 31;

    const int dst = succ[gidx];
    const float edge = dist[(size_t)(b * NG + src) * NG + dst];
    const uint4* Qr = (const uint4*)(QKb + (size_t)(b * NG + src) * 256);
    const uint4* Kr = (const uint4*)(QKb + (size_t)(b * NG + dst) * 256 + 128);

    float e = 0.f;
#pragma unroll
    for (int h = 0; h < NH; ++h) {
        float d = 0.f;
#pragma unroll
        for (int c = 0; c < 2; ++c) {
            const uint4 q = Qr[h * 2 + c];
            const uint4 k = Kr[h * 2 + c];
            d += bflo(q.x) * bflo(k.x) + bfhi(q.x) * bfhi(k.x);
            d += bflo(q.y) * bflo(k.y) + bfhi(q.y) * bfhi(k.y);
            d += bflo(q.z) * bflo(k.z) + bfhi(q.z) * bfhi(k.z);
            d += bflo(q.w) * bflo(k.w) + bfhi(q.w) * bfhi(k.w);
        }
        d *= 0.0625f;
        float ms2 = b2[h];
#pragma unroll
        for (int m = 0; m < MSH; ++m) {
            float v = d * w1[h][0][m] + edge * w1[h][1][m] + b1[h][m];
            v = fmaxf(v, 0.f);
            ms2 += v * w2[h][m];
        }
        e += ms2 * nw[h];
    }
    val_buf[gidx] = e / costs[sb];
    dst_buf[gidx] = dst;
}

// ---------------- Kernel C: sparse softmax + aggregate (bf16 ne) ----------------
__global__ __launch_bounds__(256) void sparse_softmax_agg(
        const float* __restrict__ val_buf, const int* __restrict__ dst_buf,
        const ushort* __restrict__ ne_b, unsigned* __restrict__ solu_b) {
    const int w = (blockIdx.x * 256 + threadIdx.x) >> 6;
    const int lane = threadIdx.x & 63;
    if (w >= NB * NG) return;
    const int b = w / NG;
    const int g = w - b * NG;

    float v[NS];
    int d[NS];
#pragma unroll
    for (int s = 0; s < NS; ++s) {
        const size_t o = (size_t)(s * NB + b) * NG + g;
        v[s] = val_buf[o];
        d[s] = dst_buf[o];
    }
    unsigned keep = (1u << NS) - 1u;
#pragma unroll
    for (int s = 1; s < NS; ++s) {
#pragma unroll
        for (int p = 0; p < s; ++p) {
            if (((keep >> s) & 1u) && ((keep >> p) & 1u) && (d[s] == d[p])) {
                v[p] += v[s];
                keep &= ~(1u << s);
            }
        }
    }
    float m = -INFINITY;
#pragma unroll
    for (int s = 0; s < NS; ++s) {
        const bool ok = ((keep >> s) & 1u) && (v[s] != 0.f);
        if (!ok) keep &= ~(1u << s);
        else m = fmaxf(m, v[s]);
    }

    float a0 = 0.f, a1 = 0.f;
    if (keep == 0u) {
        const unsigned* base = (const unsigned*)(ne_b + (size_t)b * NG * NE);
        for (int n = 0; n < NG; ++n) {
            const unsigned u = base[n * 64 + lane];
            a0 += bflo(u); a1 += bfhi(u);
        }
        const float invG = 1.f / NG;
        a0 *= invG; a1 *= invG;
    } else {
        float p[NS];
        float denom = 0.f;
#pragma unroll
        for (int s = 0; s < NS; ++s) {
            p[s] = ((keep >> s) & 1u) ? expf(v[s] - m) : 0.f;
            denom += p[s];
        }
        const float inv = 1.f / denom;
#pragma unroll
        for (int s = 0; s < NS; ++s) {
            if ((keep >> s) & 1u) {
                const unsigned u = ((const unsigned*)(ne_b + (size_t)(b * NG + d[s]) * NE))[lane];
                const float wt = p[s] * inv;
                a0 += wt * bflo(u);
                a1 += wt * bfhi(u);
            }
        }
    }
    solu_b[(size_t)w * 64 + lane] = (unsigned)f2bf(a0) | ((unsigned)f2bf(a1) << 16);
}

// ---------------- Kernel D: fused GRU via MFMA ----------------
__global__ __launch_bounds__(512) void gru_mfma(
        const ushort* __restrict__ x_b,
        const float* __restrict__ h_in,
        const ushort* __restrict__ wih_b, const ushort* __restrict__ whh_b,
        const float* __restrict__ bih, const float* __restrict__ bhh,
        float* __restrict__ out0, float* __restrict__ out1) {
    __shared__ __align__(16) ushort X[32 * 128];
    __shared__ __align__(16) ushort H[32 * 128];
    const int tid = threadIdx.x;
    const int rowbase = blockIdx.x * 32;

    {
        const int r = tid >> 4, kc = tid & 15;
        us8 xv = *(const us8*)&x_b[(size_t)(rowbase + r) * NE + kc * 8];
        *(us8*)&X[(r * 16 + (kc ^ (r & 7))) * 8] = xv;
        const float4* h4 = (const float4*)(h_in + (size_t)(rowbase + r) * NE);
        const float4 f0 = h4[kc * 2], f1 = h4[kc * 2 + 1];
        us8 hv;
        hv[0] = f2bf(f0.x); hv[1] = f2bf(f0.y); hv[2] = f2bf(f0.z); hv[3] = f2bf(f0.w);
        hv[4] = f2bf(f1.x); hv[5] = f2bf(f1.y); hv[6] = f2bf(f1.z); hv[7] = f2bf(f1.w);
        *(us8*)&H[(r * 16 + (kc ^ (r & 7))) * 8] = hv;
    }
    __syncthreads();

    const int w = tid >> 6, l = tid & 63;
    const int lr = l & 15, lg = l >> 4;
    const int j = w * 16 + lr;

    f32x4 acc[2][6] = {};
#pragma unroll
    for (int ks = 0; ks < 4; ++ks) {
        bf16x8 ax[2], ah[2], bb[6];
#pragma unroll
        for (int mf = 0; mf < 2; ++mf) {
            const int r = mf * 16 + lr;
            const int c = (r * 16 + ((ks * 4 + lg) ^ (r & 7))) * 8;
            ax[mf] = *(const bf16x8*)&X[c];
            ah[mf] = *(const bf16x8*)&H[c];
        }
#pragma unroll
        for (int g = 0; g < 3; ++g) {
            bb[g]     = *(const bf16x8*)&wih_b[(size_t)(g * 128 + j) * 128 + ks * 32 + lg * 8];
            bb[g + 3] = *(const bf16x8*)&whh_b[(size_t)(g * 128 + j) * 128 + ks * 32 + lg * 8];
        }
#pragma unroll
        for (int mf = 0; mf < 2; ++mf) {
#pragma unroll
            for (int g = 0; g < 3; ++g) {
                acc[mf][g]     = __builtin_amdgcn_mfma_f32_16x16x32_bf16(ax[mf], bb[g],     acc[mf][g],     0, 0, 0);
                acc[mf][g + 3] = __builtin_amdgcn_mfma_f32_16x16x32_bf16(ah[mf], bb[g + 3], acc[mf][g + 3], 0, 0, 0);
            }
        }
    }

    const float bi0 = bih[j], bi1 = bih[128 + j], bi2 = bih[256 + j];
    const float bh0 = bhh[j], bh1 = bhh[128 + j], bh2 = bhh[256 + j];
#pragma unroll
    for (int mf = 0; mf < 2; ++mf) {
#pragma unroll
        for (int q = 0; q < 4; ++q) {
            const int row = rowbase + mf * 16 + lg * 4 + q;
            const float ir = acc[mf][0][q] + bi0;
            const float iz = acc[mf][1][q] + bi1;
            const float in_ = acc[mf][2][q] + bi2;
            const float hr = acc[mf][3][q] + bh0;
            const float hz = acc[mf][4][q] + bh1;
            const float hn = acc[mf][5][q] + bh2;
            const float rr = 1.f / (1.f + expf(-(ir + hr)));
            const float zz = 1.f / (1.f + expf(-(iz + hz)));
            const float nn = tanhf(in_ + rr * hn);
            const float hv = h_in[(size_t)row * NE + j];
            const float nv = (1.f - zz) * nn + zz * hv;
            const size_t o = (size_t)row * NE + j;
            out1[o] = nv;
            out0[o] = (nv > 0.f) ? nv : expm1f(nv);
        }
    }
}

extern "C" void kernel_launch(void* const* d_in, const int* in_sizes, int n_in,
                              void* d_out, int out_size, void* d_ws, size_t ws_size,
                              hipStream_t stream) {
    const float* ne    = (const float*)d_in[0];
    const int*   sol   = (const int*)d_in[1];
    const float* costs = (const float*)d_in[2];
    const float* dist  = (const float*)d_in[3];
    const float* old_h = (const float*)d_in[4];
    const float* Wq    = (const float*)d_in[5];
    const float* Wk    = (const float*)d_in[6];
    const float* m1w   = (const float*)d_in[7];
    const float* m1b   = (const float*)d_in[8];
    const float* m2w   = (const float*)d_in[9];
    const float* m2b   = (const float*)d_in[10];
    const float* nhw   = (const float*)d_in[11];
    const float* wih   = (const float*)d_in[12];
    const float* whh   = (const float*)d_in[13];
    const float* bih   = (const float*)d_in[14];
    const float* bhh   = (const float*)d_in[15];

    float* out0 = (float*)d_out;
    float* out1 = out0 + (size_t)NB * NG * NE;

    // workspace layout (16B aligned)
    ushort*   QKb     = (ushort*)d_ws;                                // 16.384 MB
    ushort*   ne_b    = QKb + (size_t)NB * NG * 256;                  // 8.192 MB
    float*    val_buf = (float*)(ne_b + (size_t)NB * NG * NE);        // 1.28 MB
    int*      dst_buf = (int*)(val_buf + (size_t)NS * NB * NG);       // 1.28 MB
    int*      succ    = dst_buf + (size_t)NS * NB * NG;               // 1.28 MB
    unsigned* solu_b  = (unsigned*)(succ + (size_t)NS * NB * NG);     // 8.192 MB
    ushort*   Wqk_b   = (ushort*)(solu_b + (size_t)NB * NG * 64);     // 64 KB
    ushort*   wih_b   = Wqk_b + 256 * 128;                            // 96 KB
    ushort*   whh_b   = wih_b + 384 * 128;                            // 96 KB

    wcvt<<<64, 256, 0, stream>>>(Wq, Wk, wih, whh, Wqk_b, wih_b, whh_b);
    succ_build<<<(NS * NB * NG + 255) / 256, 256, 0, stream>>>(sol, succ);
    qk_mfma<<<(NB * NG) / 32, 512, 0, stream>>>(ne, Wqk_b, QKb, ne_b);
    edge_score2<<<(NS * NB * NG + 255) / 256, 256, 0, stream>>>(
        succ, costs, dist, QKb, m1w, m1b, m2w, m2b, nhw, val_buf, dst_buf);
    sparse_softmax_agg<<<(NB * NG * 64) / 256, 256, 0, stream>>>(
        val_buf, dst_buf, ne_b, solu_b);
    gru_mfma<<<(NB * NG) / 32, 512, 0, stream>>>(
        (const ushort*)solu_b, old_h, wih_b, whh_b, bih, bhh, out0, out1);
}

// Round 5
// 134.732 us; speedup vs baseline: 3.1293x; 1.1876x over previous
//
#include <hip/hip_runtime.h>
#include <math.h>

#define NS 10
#define NB 32
#define NG 1000
#define NE 128
#define NH 8
#define MSH 16

typedef __bf16 bf16x8 __attribute__((ext_vector_type(8)));
typedef float f32x4 __attribute__((ext_vector_type(4)));
typedef unsigned short ushort;
typedef ushort us8 __attribute__((ext_vector_type(8)));

__device__ __forceinline__ ushort f2bf(float f) {
    union { float f; unsigned u; } c; c.f = f;
    unsigned r = c.u + 0x7FFFu + ((c.u >> 16) & 1u);
    return (ushort)(r >> 16);
}
__device__ __forceinline__ float bflo(unsigned u) {
    union { unsigned v; float f; } c; c.v = u << 16; return c.f;
}
__device__ __forceinline__ float bfhi(unsigned u) {
    union { unsigned v; float f; } c; c.v = u & 0xFFFF0000u; return c.f;
}
__device__ __forceinline__ float dot8(uint4 q, uint4 k) {
    return bflo(q.x) * bflo(k.x) + bfhi(q.x) * bfhi(k.x)
         + bflo(q.y) * bflo(k.y) + bfhi(q.y) * bfhi(k.y)
         + bflo(q.z) * bflo(k.z) + bfhi(q.z) * bfhi(k.z)
         + bflo(q.w) * bflo(k.w) + bfhi(q.w) * bfhi(k.w);
}

// ---------------- prep: succ scatter + weight f32->bf16 ----------------
// blocks [0,1250): succ[s][b][src]=dst.  blocks [1250,1314): weight convert.
__global__ __launch_bounds__(256) void prep(const int* __restrict__ sol,
                                            const float* __restrict__ Wq,
                                            const float* __restrict__ Wk,
                                            const float* __restrict__ wih,
                                            const float* __restrict__ whh,
                                            int* __restrict__ succ,
                                            ushort* __restrict__ Wqk_b,
                                            ushort* __restrict__ wih_b,
                                            ushort* __restrict__ whh_b) {
    const int bid = blockIdx.x;
    const int tid = threadIdx.x;
    if (bid < 1250) {
        const int gidx = bid * 256 + tid;              // (s*NB+b)*NG + t
        const int sb = gidx / NG;
        const int t = gidx - sb * NG;
        const int* srow = sol + (size_t)sb * NG;
        const int src = srow[t];
        const int tn = (t + 1 == NG) ? 0 : t + 1;
        succ[(size_t)sb * NG + src] = srow[tn];
    } else {
        const int wt = (bid - 1250) * 256 + tid;       // 16384 chunk threads
        const int e = wt * 8;
        const float* src; ushort* dst; int off;
        if (e < 16384)       { src = Wq;  dst = Wqk_b;         off = e; }
        else if (e < 32768)  { src = Wk;  dst = Wqk_b + 16384; off = e - 16384; }
        else if (e < 81920)  { src = wih; dst = wih_b;         off = e - 32768; }
        else                 { src = whh; dst = whh_b;         off = e - 81920; }
        const float4 f0 = ((const float4*)(src + off))[0];
        const float4 f1 = ((const float4*)(src + off))[1];
        us8 v;
        v[0] = f2bf(f0.x); v[1] = f2bf(f0.y); v[2] = f2bf(f0.z); v[3] = f2bf(f0.w);
        v[4] = f2bf(f1.x); v[5] = f2bf(f1.y); v[6] = f2bf(f1.z); v[7] = f2bf(f1.w);
        *(us8*)(dst + off) = v;
    }
}

// ---------------- Kernel A: Q/K projection via MFMA -> bf16 ----------------
__global__ __launch_bounds__(512) void qk_mfma(const float* __restrict__ ne,
                                               const ushort* __restrict__ Wqk_b,
                                               ushort* __restrict__ QKb,
                                               ushort* __restrict__ ne_b) {
    __shared__ __align__(16) ushort A[32 * 128];
    const int tid = threadIdx.x;
    const int rowbase = blockIdx.x * 32;

    {
        const int r = tid >> 4, kc = tid & 15;
        const float4* s4 = (const float4*)(ne + (size_t)(rowbase + r) * NE);
        const float4 f0 = s4[kc * 2], f1 = s4[kc * 2 + 1];
        us8 v;
        v[0] = f2bf(f0.x); v[1] = f2bf(f0.y); v[2] = f2bf(f0.z); v[3] = f2bf(f0.w);
        v[4] = f2bf(f1.x); v[5] = f2bf(f1.y); v[6] = f2bf(f1.z); v[7] = f2bf(f1.w);
        *(us8*)&A[(r * 16 + (kc ^ (r & 7))) * 8] = v;
        *(us8*)&ne_b[(size_t)(rowbase + r) * NE + kc * 8] = v;
    }
    __syncthreads();

    const int w = tid >> 6, l = tid & 63;
    const int lr = l & 15, lg = l >> 4;

    f32x4 acc[2][2] = {};
#pragma unroll
    for (int ks = 0; ks < 4; ++ks) {
        bf16x8 a[2], b[2];
#pragma unroll
        for (int mf = 0; mf < 2; ++mf) {
            const int r = mf * 16 + lr;
            a[mf] = *(const bf16x8*)&A[(r * 16 + ((ks * 4 + lg) ^ (r & 7))) * 8];
        }
#pragma unroll
        for (int nf = 0; nf < 2; ++nf) {
            const int j = w * 32 + nf * 16 + lr;
            b[nf] = *(const bf16x8*)&Wqk_b[(size_t)j * 128 + ks * 32 + lg * 8];
        }
#pragma unroll
        for (int mf = 0; mf < 2; ++mf)
#pragma unroll
            for (int nf = 0; nf < 2; ++nf)
                acc[mf][nf] = __builtin_amdgcn_mfma_f32_16x16x32_bf16(a[mf], b[nf], acc[mf][nf], 0, 0, 0);
    }
#pragma unroll
    for (int mf = 0; mf < 2; ++mf)
#pragma unroll
        for (int nf = 0; nf < 2; ++nf)
#pragma unroll
            for (int q = 0; q < 4; ++q) {
                const int row = rowbase + mf * 16 + lg * 4 + q;
                const int col = w * 32 + nf * 16 + lr;
                QKb[(size_t)row * 256 + col] = f2bf(acc[mf][nf][q]);
            }
}

// ---------------- Kernel C: fused edge-score + softmax + aggregate ----------
// One wave per (b,g) row. Lane = (solution group sg = lane>>3, head h = lane&7).
// Pass 0: s = sg (0..7); pass 1 (lanes 0..15): s = 8+sg. shfl_xor reduce over
// h, shfl broadcast -> per-wave 10 (dst,val); merge/softmax/aggregate in-wave.
__global__ __launch_bounds__(256) void score_agg(
        const int* __restrict__ succ, const float* __restrict__ costs,
        const float* __restrict__ dist, const ushort* __restrict__ QKb,
        const ushort* __restrict__ ne_b,
        const float* __restrict__ m1w, const float* __restrict__ m1b,
        const float* __restrict__ m2w, const float* __restrict__ m2b,
        const float* __restrict__ nhw,
        unsigned* __restrict__ solu_b) {
    // transposed MLP weights: [m][h] so the 8 h-lanes hit 8 distinct banks
    __shared__ float w1t[2][MSH][NH];
    __shared__ float b1t[MSH][NH];
    __shared__ float w2t[MSH][NH];
    __shared__ float b2s[NH];
    __shared__ float nws[NH];
    const int tid = threadIdx.x;
    {   // m1w layout [h][e][m]
        const int h = tid >> 5, e = (tid >> 4) & 1, m = tid & 15;
        w1t[e][m][h] = m1w[tid];
        if (tid < 128) {
            const int h2 = tid >> 4, m2 = tid & 15;
            b1t[m2][h2] = m1b[tid];
            w2t[m2][h2] = m2w[tid];
        }
        if (tid < NH) { b2s[tid] = m2b[tid]; nws[tid] = nhw[tid]; }
    }
    __syncthreads();

    const int w = (blockIdx.x * 256 + tid) >> 6;   // 32000 waves exactly
    const int lane = tid & 63;
    const int b = w / NG;
    const int g = w - b * NG;
    const int h = lane & 7;
    const int sg = lane >> 3;

    const uint4* Qrow = (const uint4*)(QKb + (size_t)(b * NG + g) * 256);
    const uint4 q0 = Qrow[h * 2], q1 = Qrow[h * 2 + 1];

    float val_p[2]; int dst_p[2];
#pragma unroll
    for (int pass = 0; pass < 2; ++pass) {
        const int s = (pass == 0) ? sg : 8 + sg;
        const bool active = (pass == 0) || (sg < 2);
        float val = 0.f; int dst = 0;
        if (active) {
            dst = succ[(size_t)(s * NB + b) * NG + g];
            const float edge = dist[(size_t)(b * NG + g) * NG + dst];
            const uint4* Kr = (const uint4*)(QKb + (size_t)(b * NG + dst) * 256 + 128);
            const uint4 k0 = Kr[h * 2], k1 = Kr[h * 2 + 1];
            float d = (dot8(q0, k0) + dot8(q1, k1)) * 0.0625f;
            float ms2 = b2s[h];
#pragma unroll
            for (int m = 0; m < MSH; ++m) {
                float t = d * w1t[0][m][h] + edge * w1t[1][m][h] + b1t[m][h];
                t = fmaxf(t, 0.f);
                ms2 += t * w2t[m][h];
            }
            float contrib = ms2 * nws[h];
            contrib += __shfl_xor(contrib, 1);
            contrib += __shfl_xor(contrib, 2);
            contrib += __shfl_xor(contrib, 4);
            val = contrib / costs[s * NB + b];
        }
        val_p[pass] = val; dst_p[pass] = dst;
    }

    float v[NS]; int d[NS];
#pragma unroll
    for (int s = 0; s < 8; ++s) {
        v[s] = __shfl(val_p[0], s * 8);
        d[s] = __shfl(dst_p[0], s * 8);
    }
    v[8] = __shfl(val_p[1], 0); d[8] = __shfl(dst_p[1], 0);
    v[9] = __shfl(val_p[1], 8); d[9] = __shfl(dst_p[1], 8);

    unsigned keep = (1u << NS) - 1u;
#pragma unroll
    for (int s = 1; s < NS; ++s) {
#pragma unroll
        for (int p = 0; p < s; ++p) {
            if (((keep >> s) & 1u) && ((keep >> p) & 1u) && (d[s] == d[p])) {
                v[p] += v[s];
                keep &= ~(1u << s);
            }
        }
    }
    float m = -INFINITY;
#pragma unroll
    for (int s = 0; s < NS; ++s) {
        const bool ok = ((keep >> s) & 1u) && (v[s] != 0.f);
        if (!ok) keep &= ~(1u << s);
        else m = fmaxf(m, v[s]);
    }

    float a0 = 0.f, a1 = 0.f;
    if (keep == 0u) {
        const unsigned* base = (const unsigned*)(ne_b + (size_t)b * NG * NE);
        for (int n = 0; n < NG; ++n) {
            const unsigned u = base[n * 64 + lane];
            a0 += bflo(u); a1 += bfhi(u);
        }
        const float invG = 1.f / NG;
        a0 *= invG; a1 *= invG;
    } else {
        float p[NS];
        float denom = 0.f;
#pragma unroll
        for (int s = 0; s < NS; ++s) {
            p[s] = ((keep >> s) & 1u) ? expf(v[s] - m) : 0.f;
            denom += p[s];
        }
        const float inv = 1.f / denom;
#pragma unroll
        for (int s = 0; s < NS; ++s) {
            if ((keep >> s) & 1u) {
                const unsigned u = ((const unsigned*)(ne_b + (size_t)(b * NG + d[s]) * NE))[lane];
                const float wt = p[s] * inv;
                a0 += wt * bflo(u);
                a1 += wt * bfhi(u);
            }
        }
    }
    solu_b[(size_t)w * 64 + lane] = (unsigned)f2bf(a0) | ((unsigned)f2bf(a1) << 16);
}

// ---------------- Kernel D: fused GRU via MFMA ----------------
__global__ __launch_bounds__(512) void gru_mfma(
        const ushort* __restrict__ x_b,
        const float* __restrict__ h_in,
        const ushort* __restrict__ wih_b, const ushort* __restrict__ whh_b,
        const float* __restrict__ bih, const float* __restrict__ bhh,
        float* __restrict__ out0, float* __restrict__ out1) {
    __shared__ __align__(16) ushort X[32 * 128];
    __shared__ __align__(16) ushort H[32 * 128];
    const int tid = threadIdx.x;
    const int rowbase = blockIdx.x * 32;

    {
        const int r = tid >> 4, kc = tid & 15;
        us8 xv = *(const us8*)&x_b[(size_t)(rowbase + r) * NE + kc * 8];
        *(us8*)&X[(r * 16 + (kc ^ (r & 7))) * 8] = xv;
        const float4* h4 = (const float4*)(h_in + (size_t)(rowbase + r) * NE);
        const float4 f0 = h4[kc * 2], f1 = h4[kc * 2 + 1];
        us8 hv;
        hv[0] = f2bf(f0.x); hv[1] = f2bf(f0.y); hv[2] = f2bf(f0.z); hv[3] = f2bf(f0.w);
        hv[4] = f2bf(f1.x); hv[5] = f2bf(f1.y); hv[6] = f2bf(f1.z); hv[7] = f2bf(f1.w);
        *(us8*)&H[(r * 16 + (kc ^ (r & 7))) * 8] = hv;
    }
    __syncthreads();

    const int w = tid >> 6, l = tid & 63;
    const int lr = l & 15, lg = l >> 4;
    const int j = w * 16 + lr;

    f32x4 acc[2][6] = {};
#pragma unroll
    for (int ks = 0; ks < 4; ++ks) {
        bf16x8 ax[2], ah[2], bb[6];
#pragma unroll
        for (int mf = 0; mf < 2; ++mf) {
            const int r = mf * 16 + lr;
            const int c = (r * 16 + ((ks * 4 + lg) ^ (r & 7))) * 8;
            ax[mf] = *(const bf16x8*)&X[c];
            ah[mf] = *(const bf16x8*)&H[c];
        }
#pragma unroll
        for (int g = 0; g < 3; ++g) {
            bb[g]     = *(const bf16x8*)&wih_b[(size_t)(g * 128 + j) * 128 + ks * 32 + lg * 8];
            bb[g + 3] = *(const bf16x8*)&whh_b[(size_t)(g * 128 + j) * 128 + ks * 32 + lg * 8];
        }
#pragma unroll
        for (int mf = 0; mf < 2; ++mf) {
#pragma unroll
            for (int g = 0; g < 3; ++g) {
                acc[mf][g]     = __builtin_amdgcn_mfma_f32_16x16x32_bf16(ax[mf], bb[g],     acc[mf][g],     0, 0, 0);
                acc[mf][g + 3] = __builtin_amdgcn_mfma_f32_16x16x32_bf16(ah[mf], bb[g + 3], acc[mf][g + 3], 0, 0, 0);
            }
        }
    }

    const float bi0 = bih[j], bi1 = bih[128 + j], bi2 = bih[256 + j];
    const float bh0 = bhh[j], bh1 = bhh[128 + j], bh2 = bhh[256 + j];
#pragma unroll
    for (int mf = 0; mf < 2; ++mf) {
#pragma unroll
        for (int q = 0; q < 4; ++q) {
            const int row = rowbase + mf * 16 + lg * 4 + q;
            const float ir = acc[mf][0][q] + bi0;
            const float iz = acc[mf][1][q] + bi1;
            const float in_ = acc[mf][2][q] + bi2;
            const float hr = acc[mf][3][q] + bh0;
            const float hz = acc[mf][4][q] + bh1;
            const float hn = acc[mf][5][q] + bh2;
            const float rr = 1.f / (1.f + expf(-(ir + hr)));
            const float zz = 1.f / (1.f + expf(-(iz + hz)));
            const float nn = tanhf(in_ + rr * hn);
            const float hv = h_in[(size_t)row * NE + j];
            const float nv = (1.f - zz) * nn + zz * hv;
            const size_t o = (size_t)row * NE + j;
            out1[o] = nv;
            out0[o] = (nv > 0.f) ? nv : expm1f(nv);
        }
    }
}

extern "C" void kernel_launch(void* const* d_in, const int* in_sizes, int n_in,
                              void* d_out, int out_size, void* d_ws, size_t ws_size,
                              hipStream_t stream) {
    const float* ne    = (const float*)d_in[0];
    const int*   sol   = (const int*)d_in[1];
    const float* costs = (const float*)d_in[2];
    const float* dist  = (const float*)d_in[3];
    const float* old_h = (const float*)d_in[4];
    const float* Wq    = (const float*)d_in[5];
    const float* Wk    = (const float*)d_in[6];
    const float* m1w   = (const float*)d_in[7];
    const float* m1b   = (const float*)d_in[8];
    const float* m2w   = (const float*)d_in[9];
    const float* m2b   = (const float*)d_in[10];
    const float* nhw   = (const float*)d_in[11];
    const float* wih   = (const float*)d_in[12];
    const float* whh   = (const float*)d_in[13];
    const float* bih   = (const float*)d_in[14];
    const float* bhh   = (const float*)d_in[15];

    float* out0 = (float*)d_out;
    float* out1 = out0 + (size_t)NB * NG * NE;

    // workspace layout (16B aligned)
    ushort*   QKb     = (ushort*)d_ws;                                // 16.384 MB
    ushort*   ne_b    = QKb + (size_t)NB * NG * 256;                  // 8.192 MB
    int*      succ    = (int*)(ne_b + (size_t)NB * NG * NE);          // 1.28 MB
    unsigned* solu_b  = (unsigned*)(succ + (size_t)NS * NB * NG);     // 8.192 MB
    ushort*   Wqk_b   = (ushort*)(solu_b + (size_t)NB * NG * 64);     // 64 KB
    ushort*   wih_b   = Wqk_b + 256 * 128;                            // 96 KB
    ushort*   whh_b   = wih_b + 384 * 128;                            // 96 KB

    prep<<<1314, 256, 0, stream>>>(sol, Wq, Wk, wih, whh, succ, Wqk_b, wih_b, whh_b);
    qk_mfma<<<(NB * NG) / 32, 512, 0, stream>>>(ne, Wqk_b, QKb, ne_b);
    score_agg<<<(NB * NG * 64) / 256, 256, 0, stream>>>(
        succ, costs, dist, QKb, ne_b, m1w, m1b, m2w, m2b, nhw, solu_b);
    gru_mfma<<<(NB * NG) / 32, 512, 0, stream>>>(
        (const ushort*)solu_b, old_h, wih_b, whh_b, bih, bhh, out0, out1);
}

// Round 6
// 105.508 us; speedup vs baseline: 3.9960x; 1.2770x over previous
//
#include <hip/hip_runtime.h>
#include <math.h>

#define NS 10
#define NB 32
#define NG 1000
#define NE 128
#define NH 8
#define MSH 16

typedef __bf16 bf16x8 __attribute__((ext_vector_type(8)));
typedef float f32x4 __attribute__((ext_vector_type(4)));
typedef unsigned short ushort;
typedef ushort us8 __attribute__((ext_vector_type(8)));

__device__ __forceinline__ ushort f2bf(float f) {
    union { float f; unsigned u; } c; c.f = f;
    unsigned r = c.u + 0x7FFFu + ((c.u >> 16) & 1u);
    return (ushort)(r >> 16);
}
__device__ __forceinline__ float bflo(unsigned u) {
    union { unsigned v; float f; } c; c.v = u << 16; return c.f;
}
__device__ __forceinline__ float bfhi(unsigned u) {
    union { unsigned v; float f; } c; c.v = u & 0xFFFF0000u; return c.f;
}
__device__ __forceinline__ float dot8(uint4 q, uint4 k) {
    return bflo(q.x) * bflo(k.x) + bfhi(q.x) * bfhi(k.x)
         + bflo(q.y) * bflo(k.y) + bfhi(q.y) * bfhi(k.y)
         + bflo(q.z) * bflo(k.z) + bfhi(q.z) * bfhi(k.z)
         + bflo(q.w) * bflo(k.w) + bfhi(q.w) * bfhi(k.w);
}

// ---------------- prep: succ scatter + weight f32->bf16 ----------------
__global__ __launch_bounds__(256) void prep(const int* __restrict__ sol,
                                            const float* __restrict__ Wq,
                                            const float* __restrict__ Wk,
                                            const float* __restrict__ wih,
                                            const float* __restrict__ whh,
                                            int* __restrict__ succ,
                                            ushort* __restrict__ Wqk_b,
                                            ushort* __restrict__ wih_b,
                                            ushort* __restrict__ whh_b) {
    const int bid = blockIdx.x;
    const int tid = threadIdx.x;
    if (bid < 1250) {
        const int gidx = bid * 256 + tid;              // (s*NB+b)*NG + t
        const int sb = gidx / NG;
        const int t = gidx - sb * NG;
        const int* srow = sol + (size_t)sb * NG;
        const int src = srow[t];
        const int tn = (t + 1 == NG) ? 0 : t + 1;
        succ[(size_t)sb * NG + src] = srow[tn];
    } else {
        const int wt = (bid - 1250) * 256 + tid;       // 16384 chunk threads
        const int e = wt * 8;
        const float* src; ushort* dst; int off;
        if (e < 16384)       { src = Wq;  dst = Wqk_b;         off = e; }
        else if (e < 32768)  { src = Wk;  dst = Wqk_b + 16384; off = e - 16384; }
        else if (e < 81920)  { src = wih; dst = wih_b;         off = e - 32768; }
        else                 { src = whh; dst = whh_b;         off = e - 81920; }
        const float4 f0 = ((const float4*)(src + off))[0];
        const float4 f1 = ((const float4*)(src + off))[1];
        us8 v;
        v[0] = f2bf(f0.x); v[1] = f2bf(f0.y); v[2] = f2bf(f0.z); v[3] = f2bf(f0.w);
        v[4] = f2bf(f1.x); v[5] = f2bf(f1.y); v[6] = f2bf(f1.z); v[7] = f2bf(f1.w);
        *(us8*)(dst + off) = v;
    }
}

// ---------------- Kernel A: Q/K projection via MFMA -> bf16 ----------------
__global__ __launch_bounds__(512) void qk_mfma(const float* __restrict__ ne,
                                               const ushort* __restrict__ Wqk_b,
                                               ushort* __restrict__ QKb,
                                               ushort* __restrict__ ne_b) {
    __shared__ __align__(16) ushort A[32 * 128];
    const int tid = threadIdx.x;
    const int rowbase = blockIdx.x * 32;

    {
        const int r = tid >> 4, kc = tid & 15;
        const float4* s4 = (const float4*)(ne + (size_t)(rowbase + r) * NE);
        const float4 f0 = s4[kc * 2], f1 = s4[kc * 2 + 1];
        us8 v;
        v[0] = f2bf(f0.x); v[1] = f2bf(f0.y); v[2] = f2bf(f0.z); v[3] = f2bf(f0.w);
        v[4] = f2bf(f1.x); v[5] = f2bf(f1.y); v[6] = f2bf(f1.z); v[7] = f2bf(f1.w);
        *(us8*)&A[(r * 16 + (kc ^ (r & 7))) * 8] = v;
        *(us8*)&ne_b[(size_t)(rowbase + r) * NE + kc * 8] = v;
    }
    __syncthreads();

    const int w = tid >> 6, l = tid & 63;
    const int lr = l & 15, lg = l >> 4;

    f32x4 acc[2][2] = {};
#pragma unroll
    for (int ks = 0; ks < 4; ++ks) {
        bf16x8 a[2], b[2];
#pragma unroll
        for (int mf = 0; mf < 2; ++mf) {
            const int r = mf * 16 + lr;
            a[mf] = *(const bf16x8*)&A[(r * 16 + ((ks * 4 + lg) ^ (r & 7))) * 8];
        }
#pragma unroll
        for (int nf = 0; nf < 2; ++nf) {
            const int j = w * 32 + nf * 16 + lr;
            b[nf] = *(const bf16x8*)&Wqk_b[(size_t)j * 128 + ks * 32 + lg * 8];
        }
#pragma unroll
        for (int mf = 0; mf < 2; ++mf)
#pragma unroll
            for (int nf = 0; nf < 2; ++nf)
                acc[mf][nf] = __builtin_amdgcn_mfma_f32_16x16x32_bf16(a[mf], b[nf], acc[mf][nf], 0, 0, 0);
    }
#pragma unroll
    for (int mf = 0; mf < 2; ++mf)
#pragma unroll
        for (int nf = 0; nf < 2; ++nf)
#pragma unroll
            for (int q = 0; q < 4; ++q) {
                const int row = rowbase + mf * 16 + lg * 4 + q;
                const int col = w * 32 + nf * 16 + lr;
                QKb[(size_t)row * 256 + col] = f2bf(acc[mf][nf][q]);
            }
}

// ---------------- Kernel C: fused edge-score + softmax + aggregate ----------
// XCD-locality mapping: all blocks of batch b land on XCD b&7 (dispatch
// round-robins XCD = bid%8). Per XCD working set: 4 batches x (512KB K +
// 256KB ne_b) = 3MB < 4MB L2.
// One wave per (b,g) row. Lane = (sg = lane>>3, head h = lane&7).
// Pass 0: s = sg; pass 1 (sg<2): s = 8+sg. All gathers hoisted before compute.
__global__ __launch_bounds__(256) void score_agg(
        const int* __restrict__ succ, const float* __restrict__ costs,
        const float* __restrict__ dist, const ushort* __restrict__ QKb,
        const ushort* __restrict__ ne_b,
        const float* __restrict__ m1w, const float* __restrict__ m1b,
        const float* __restrict__ m2w, const float* __restrict__ m2b,
        const float* __restrict__ nhw,
        unsigned* __restrict__ solu_b) {
    __shared__ float w1t[2][MSH][NH];
    __shared__ float b1t[MSH][NH];
    __shared__ float w2t[MSH][NH];
    __shared__ float b2s[NH];
    __shared__ float nws[NH];
    const int tid = threadIdx.x;
    {   // m1w layout [h][e][m] -> transposed [e][m][h]
        const int h = tid >> 5, e = (tid >> 4) & 1, m = tid & 15;
        w1t[e][m][h] = m1w[tid];
        if (tid < 128) {
            const int h2 = tid >> 4, m2 = tid & 15;
            b1t[m2][h2] = m1b[tid];
            w2t[m2][h2] = m2w[tid];
        }
        if (tid < NH) { b2s[tid] = m2b[tid]; nws[tid] = nhw[tid]; }
    }
    __syncthreads();

    // bijective XCD-aware remap: 8000 blocks -> (b, g-chunk)
    const int bid = blockIdx.x;
    const int xcd = bid & 7;
    const int idx = bid >> 3;              // [0,1000)
    const int b = xcd + 8 * (idx / 250);   // 4 batches per XCD
    const int g = (idx % 250) * 4 + (tid >> 6);
    const int lane = tid & 63;
    const int w = b * NG + g;
    const int h = lane & 7;
    const int sg = lane >> 3;

    const uint4* Qrow = (const uint4*)(QKb + (size_t)w * 256);
    const uint4 q0 = Qrow[h * 2], q1 = Qrow[h * 2 + 1];

    // ---- hoisted gathers for both passes ----
    int dstp[2];
    float edgep[2];
    uint4 k0p[2], k1p[2];
#pragma unroll
    for (int pass = 0; pass < 2; ++pass) {
        const int s = (pass == 0) ? sg : 8 + sg;
        const bool active = (pass == 0) || (sg < 2);
        int dst = 0; float edge = 0.f;
        uint4 k0 = {0,0,0,0}, k1 = {0,0,0,0};
        if (active) {
            dst = succ[(size_t)(s * NB + b) * NG + g];
            edge = dist[(size_t)w * NG + dst];
            const uint4* Kr = (const uint4*)(QKb + (size_t)(b * NG + dst) * 256 + 128);
            k0 = Kr[h * 2]; k1 = Kr[h * 2 + 1];
        }
        dstp[pass] = dst; edgep[pass] = edge; k0p[pass] = k0; k1p[pass] = k1;
    }

    // ---- compute ----
    float val_p[2];
#pragma unroll
    for (int pass = 0; pass < 2; ++pass) {
        const int s = (pass == 0) ? sg : 8 + sg;
        float d = (dot8(q0, k0p[pass]) + dot8(q1, k1p[pass])) * 0.0625f;
        float ms2 = b2s[h];
#pragma unroll
        for (int m = 0; m < MSH; ++m) {
            float t = d * w1t[0][m][h] + edgep[pass] * w1t[1][m][h] + b1t[m][h];
            t = fmaxf(t, 0.f);
            ms2 += t * w2t[m][h];
        }
        float contrib = ms2 * nws[h];
        contrib += __shfl_xor(contrib, 1);
        contrib += __shfl_xor(contrib, 2);
        contrib += __shfl_xor(contrib, 4);
        val_p[pass] = contrib / costs[s * NB + b];
    }

    float v[NS]; int d[NS];
#pragma unroll
    for (int s = 0; s < 8; ++s) {
        v[s] = __shfl(val_p[0], s * 8);
        d[s] = __shfl(dstp[0], s * 8);
    }
    v[8] = __shfl(val_p[1], 0); d[8] = __shfl(dstp[1], 0);
    v[9] = __shfl(val_p[1], 8); d[9] = __shfl(dstp[1], 8);

    unsigned keep = (1u << NS) - 1u;
#pragma unroll
    for (int s = 1; s < NS; ++s) {
#pragma unroll
        for (int p = 0; p < s; ++p) {
            if (((keep >> s) & 1u) && ((keep >> p) & 1u) && (d[s] == d[p])) {
                v[p] += v[s];
                keep &= ~(1u << s);
            }
        }
    }
    float m = -INFINITY;
#pragma unroll
    for (int s = 0; s < NS; ++s) {
        const bool ok = ((keep >> s) & 1u) && (v[s] != 0.f);
        if (!ok) keep &= ~(1u << s);
        else m = fmaxf(m, v[s]);
    }

    float a0 = 0.f, a1 = 0.f;
    if (keep == 0u) {
        const unsigned* base = (const unsigned*)(ne_b + (size_t)b * NG * NE);
        for (int n = 0; n < NG; ++n) {
            const unsigned u = base[n * 64 + lane];
            a0 += bflo(u); a1 += bfhi(u);
        }
        const float invG = 1.f / NG;
        a0 *= invG; a1 *= invG;
    } else {
        float p[NS];
        float denom = 0.f;
#pragma unroll
        for (int s = 0; s < NS; ++s) {
            p[s] = ((keep >> s) & 1u) ? expf(v[s] - m) : 0.f;
            denom += p[s];
        }
        const float inv = 1.f / denom;
#pragma unroll
        for (int s = 0; s < NS; ++s) {
            if ((keep >> s) & 1u) {
                const unsigned u = ((const unsigned*)(ne_b + (size_t)(b * NG + d[s]) * NE))[lane];
                const float wt = p[s] * inv;
                a0 += wt * bflo(u);
                a1 += wt * bfhi(u);
            }
        }
    }
    solu_b[(size_t)w * 64 + lane] = (unsigned)f2bf(a0) | ((unsigned)f2bf(a1) << 16);
}

// ---------------- Kernel D: fused GRU via MFMA ----------------
__global__ __launch_bounds__(512) void gru_mfma(
        const ushort* __restrict__ x_b,
        const float* __restrict__ h_in,
        const ushort* __restrict__ wih_b, const ushort* __restrict__ whh_b,
        const float* __restrict__ bih, const float* __restrict__ bhh,
        float* __restrict__ out0, float* __restrict__ out1) {
    __shared__ __align__(16) ushort X[32 * 128];
    __shared__ __align__(16) ushort H[32 * 128];
    const int tid = threadIdx.x;
    const int rowbase = blockIdx.x * 32;

    {
        const int r = tid >> 4, kc = tid & 15;
        us8 xv = *(const us8*)&x_b[(size_t)(rowbase + r) * NE + kc * 8];
        *(us8*)&X[(r * 16 + (kc ^ (r & 7))) * 8] = xv;
        const float4* h4 = (const float4*)(h_in + (size_t)(rowbase + r) * NE);
        const float4 f0 = h4[kc * 2], f1 = h4[kc * 2 + 1];
        us8 hv;
        hv[0] = f2bf(f0.x); hv[1] = f2bf(f0.y); hv[2] = f2bf(f0.z); hv[3] = f2bf(f0.w);
        hv[4] = f2bf(f1.x); hv[5] = f2bf(f1.y); hv[6] = f2bf(f1.z); hv[7] = f2bf(f1.w);
        *(us8*)&H[(r * 16 + (kc ^ (r & 7))) * 8] = hv;
    }
    __syncthreads();

    const int w = tid >> 6, l = tid & 63;
    const int lr = l & 15, lg = l >> 4;
    const int j = w * 16 + lr;

    f32x4 acc[2][6] = {};
#pragma unroll
    for (int ks = 0; ks < 4; ++ks) {
        bf16x8 ax[2], ah[2], bb[6];
#pragma unroll
        for (int mf = 0; mf < 2; ++mf) {
            const int r = mf * 16 + lr;
            const int c = (r * 16 + ((ks * 4 + lg) ^ (r & 7))) * 8;
            ax[mf] = *(const bf16x8*)&X[c];
            ah[mf] = *(const bf16x8*)&H[c];
        }
#pragma unroll
        for (int g = 0; g < 3; ++g) {
            bb[g]     = *(const bf16x8*)&wih_b[(size_t)(g * 128 + j) * 128 + ks * 32 + lg * 8];
            bb[g + 3] = *(const bf16x8*)&whh_b[(size_t)(g * 128 + j) * 128 + ks * 32 + lg * 8];
        }
#pragma unroll
        for (int mf = 0; mf < 2; ++mf) {
#pragma unroll
            for (int g = 0; g < 3; ++g) {
                acc[mf][g]     = __builtin_amdgcn_mfma_f32_16x16x32_bf16(ax[mf], bb[g],     acc[mf][g],     0, 0, 0);
                acc[mf][g + 3] = __builtin_amdgcn_mfma_f32_16x16x32_bf16(ah[mf], bb[g + 3], acc[mf][g + 3], 0, 0, 0);
            }
        }
    }

    const float bi0 = bih[j], bi1 = bih[128 + j], bi2 = bih[256 + j];
    const float bh0 = bhh[j], bh1 = bhh[128 + j], bh2 = bhh[256 + j];
#pragma unroll
    for (int mf = 0; mf < 2; ++mf) {
#pragma unroll
        for (int q = 0; q < 4; ++q) {
            const int row = rowbase + mf * 16 + lg * 4 + q;
            const float ir = acc[mf][0][q] + bi0;
            const float iz = acc[mf][1][q] + bi1;
            const float in_ = acc[mf][2][q] + bi2;
            const float hr = acc[mf][3][q] + bh0;
            const float hz = acc[mf][4][q] + bh1;
            const float hn = acc[mf][5][q] + bh2;
            const float rr = 1.f / (1.f + expf(-(ir + hr)));
            const float zz = 1.f / (1.f + expf(-(iz + hz)));
            const float nn = tanhf(in_ + rr * hn);
            const float hv = h_in[(size_t)row * NE + j];
            const float nv = (1.f - zz) * nn + zz * hv;
            const size_t o = (size_t)row * NE + j;
            out1[o] = nv;
            out0[o] = (nv > 0.f) ? nv : expm1f(nv);
        }
    }
}

extern "C" void kernel_launch(void* const* d_in, const int* in_sizes, int n_in,
                              void* d_out, int out_size, void* d_ws, size_t ws_size,
                              hipStream_t stream) {
    const float* ne    = (const float*)d_in[0];
    const int*   sol   = (const int*)d_in[1];
    const float* costs = (const float*)d_in[2];
    const float* dist  = (const float*)d_in[3];
    const float* old_h = (const float*)d_in[4];
    const float* Wq    = (const float*)d_in[5];
    const float* Wk    = (const float*)d_in[6];
    const float* m1w   = (const float*)d_in[7];
    const float* m1b   = (const float*)d_in[8];
    const float* m2w   = (const float*)d_in[9];
    const float* m2b   = (const float*)d_in[10];
    const float* nhw   = (const float*)d_in[11];
    const float* wih   = (const float*)d_in[12];
    const float* whh   = (const float*)d_in[13];
    const float* bih   = (const float*)d_in[14];
    const float* bhh   = (const float*)d_in[15];

    float* out0 = (float*)d_out;
    float* out1 = out0 + (size_t)NB * NG * NE;

    // workspace layout (16B aligned)
    ushort*   QKb     = (ushort*)d_ws;                                // 16.384 MB
    ushort*   ne_b    = QKb + (size_t)NB * NG * 256;                  // 8.192 MB
    int*      succ    = (int*)(ne_b + (size_t)NB * NG * NE);          // 1.28 MB
    unsigned* solu_b  = (unsigned*)(succ + (size_t)NS * NB * NG);     // 8.192 MB
    ushort*   Wqk_b   = (ushort*)(solu_b + (size_t)NB * NG * 64);     // 64 KB
    ushort*   wih_b   = Wqk_b + 256 * 128;                            // 96 KB
    ushort*   whh_b   = wih_b + 384 * 128;                            // 96 KB

    prep<<<1314, 256, 0, stream>>>(sol, Wq, Wk, wih, whh, succ, Wqk_b, wih_b, whh_b);
    qk_mfma<<<(NB * NG) / 32, 512, 0, stream>>>(ne, Wqk_b, QKb, ne_b);
    score_agg<<<(NB * NG * 64) / 256, 256, 0, stream>>>(
        succ, costs, dist, QKb, ne_b, m1w, m1b, m2w, m2b, nhw, solu_b);
    gru_mfma<<<(NB * NG) / 32, 512, 0, stream>>>(
        (const ushort*)solu_b, old_h, wih_b, whh_b, bih, bhh, out0, out1);
}